// Round 9
// baseline (585.593 us; speedup 1.0000x reference)
//
#include <hip/hip_runtime.h>

#define N_NODES 50000
#define N_EDGES 1600000
#define HID     128
#define N_GRAPHS 64

#define HIST_BLOCKS 128
#define EPB (N_EDGES / HIST_BLOCKS)      // 12500 edges per block
#define NWORDS 25000                     // 50000 nodes packed 2-per-u32
#define FILL_PASSES 4
#define NPP 12500                        // nodes per fill pass
#define WPP (NPP / 2)                    // 6250 cursor words per pass

// workspace layout (4-byte words) — 8.2M words = 32.8 MB
#define WS_DEG   0u         // int[50000]
#define WS_BSUM  50000u     // int[256]
#define WS_BOFF  50256u     // int[256]
#define WS_OFFS  50512u     // int[50000]
#define WS_INVD  100512u    // float[50000]
#define WS_CSR   150512u    // int[1600000]
#define WS_XB_B  1750512u   // uint[3200000]: hist[128][25000] during build; x ping buffer B after
#define WS_XB_A  4950512u   // uint[3200000]: x ping buffer A (bf16 x2: 50000x128)
#define WS_WP    8150512u   // uint[49152] = packed W frags: 3 layers x 4096 uint4
#define WS_END   8199664u

typedef __attribute__((ext_vector_type(8))) short short8;
typedef __attribute__((ext_vector_type(4))) float floatx4;

// ---- bf16 helpers (raw, RN-even pack; fp32 math everywhere) ----
__device__ __forceinline__ float bf_lo(unsigned u) { return __uint_as_float(u << 16); }
__device__ __forceinline__ float bf_hi(unsigned u) { return __uint_as_float(u & 0xffff0000u); }
__device__ __forceinline__ unsigned bf_rn(float f) {
    unsigned u = __float_as_uint(f);
    unsigned r = ((u >> 16) & 1u) + 0x7fffu;
    return (u + r) >> 16;
}
__device__ __forceinline__ unsigned bf_pack(float lo, float hi) {
    return bf_rn(lo) | (bf_rn(hi) << 16);
}

// ---------------- x0 fp32 -> bf16 ----------------
__global__ __launch_bounds__(256) void k_cvt(const float4* __restrict__ x, uint2* __restrict__ o) {
    int i = blockIdx.x * 256 + threadIdx.x;      // 1.6M total
    float4 v = x[i];
    uint2 r;
    r.x = bf_pack(v.x, v.y);
    r.y = bf_pack(v.z, v.w);
    o[i] = r;
}

// ---------------- W pre-pack into MFMA B-fragment order ----------------
__global__ __launch_bounds__(256) void k_packw(const float* __restrict__ Wn, const float* __restrict__ Wr,
                                               uint4* __restrict__ wp) {
    int idx = blockIdx.x * 256 + threadIdx.x;    // 12288 total
    int layer = idx >> 12;
    int rem = idx & 4095;
    int kb = rem >> 9;
    int n = (rem >> 2) & 127;
    int quad = rem & 3;
    float v[8];
#pragma unroll
    for (int j = 0; j < 8; j++) {
        int k = kb * 32 + quad * 8 + j;
        v[j] = (k < 128) ? Wn[layer * 16384 + k * 128 + n]
                         : Wr[layer * 16384 + (k - 128) * 128 + n];
    }
    uint4 r;
    r.x = bf_pack(v[0], v[1]);
    r.y = bf_pack(v[2], v[3]);
    r.z = bf_pack(v[4], v[5]);
    r.w = bf_pack(v[6], v[7]);
    wp[idx] = r;
}

// ---------------- CSR build: atomic-free (LDS histograms + block-partial scan) ----------------

__global__ __launch_bounds__(256) void k_hist(const int* __restrict__ ei, unsigned* __restrict__ hist) {
    __shared__ unsigned sh[NWORDS];
    for (int i = threadIdx.x; i < NWORDS; i += 256) sh[i] = 0;
    __syncthreads();
    const int e0 = blockIdx.x * EPB;
    for (int i = threadIdx.x; i < EPB; i += 256) {
        int d = __builtin_nontemporal_load(ei + N_EDGES + e0 + i);
        atomicAdd(&sh[d >> 1], 1u << ((d & 1) << 4));
    }
    __syncthreads();
    unsigned* hb = hist + (size_t)blockIdx.x * NWORDS;
    for (int i = threadIdx.x; i < NWORDS; i += 256) hb[i] = sh[i];
}

__global__ __launch_bounds__(256) void k_scanb(unsigned* __restrict__ hist, int* __restrict__ deg) {
    int w = blockIdx.x * 256 + threadIdx.x;
    if (w >= NWORDS) return;
    unsigned run = 0;
#pragma unroll 8
    for (int b = 0; b < HIST_BLOCKS; ++b) {
        unsigned u = hist[(size_t)b * NWORDS + w];
        hist[(size_t)b * NWORDS + w] = run;
        run += u;
    }
    deg[2 * w] = (int)(run & 0xffffu);
    deg[2 * w + 1] = (int)(run >> 16);
}

__global__ __launch_bounds__(256) void k_blockreduce(const int* __restrict__ deg, int* __restrict__ bsum) {
    __shared__ int s[256];
    int i = blockIdx.x * 256 + threadIdx.x;
    s[threadIdx.x] = (i < N_NODES) ? deg[i] : 0;
    __syncthreads();
    for (int d = 128; d > 0; d >>= 1) {
        if (threadIdx.x < d) s[threadIdx.x] += s[threadIdx.x + d];
        __syncthreads();
    }
    if (threadIdx.x == 0) bsum[blockIdx.x] = s[0];
}

__global__ __launch_bounds__(256) void k_scanblocks(const int* __restrict__ bsum, int* __restrict__ boff, int nb) {
    __shared__ int s[256];
    int t = threadIdx.x;
    int v = (t < nb) ? bsum[t] : 0;
    s[t] = v;
    __syncthreads();
    for (int d = 1; d < 256; d <<= 1) {
        int add = (t >= d) ? s[t - d] : 0;
        __syncthreads();
        s[t] += add;
        __syncthreads();
    }
    if (t < nb) boff[t] = s[t] - v;   // exclusive
}

__global__ __launch_bounds__(256) void k_offsets(const int* __restrict__ deg, const int* __restrict__ boff,
                                                 int* __restrict__ offs, float* __restrict__ invdeg) {
    __shared__ int s[256];
    int b = blockIdx.x, t = threadIdx.x;
    int i = b * 256 + t;
    int v = (i < N_NODES) ? deg[i] : 0;
    s[t] = v;
    __syncthreads();
    for (int d = 1; d < 256; d <<= 1) {
        int add = (t >= d) ? s[t - d] : 0;
        __syncthreads();
        s[t] += add;
        __syncthreads();
    }
    if (i < N_NODES) {
        offs[i] = boff[b] + s[t] - v;   // exclusive global offset
        invdeg[i] = 1.0f / fmaxf((float)v, 1.0f);
    }
}

// Stage 3: fill — all 4 node-range passes concurrent; LDS atomics only.
// csr stores PRE-SCALED src uint4-offsets (src*16).
__global__ __launch_bounds__(256) void k_fill2(const int* __restrict__ ei, const int* __restrict__ offs,
                                               const unsigned* __restrict__ hist, int* __restrict__ csr) {
    __shared__ unsigned scur[WPP];   // 25 KB
    const int s8 = blockIdx.x & 7;
    const int pass = s8 >> 1;                              // 0..3
    const int b = ((blockIdx.x >> 3) << 1) | (s8 & 1);     // 0..127 edge slice
    const int nbase = pass * NPP;
    const unsigned* hb = hist + (size_t)b * NWORDS + pass * WPP;
    for (int i = threadIdx.x; i < WPP; i += 256) scur[i] = hb[i];
    __syncthreads();
    const int e0 = b * EPB;
    for (int i = threadIdx.x; i < EPB; i += 256) {
        int d = __builtin_nontemporal_load(ei + N_EDGES + e0 + i);
        unsigned rd = (unsigned)(d - nbase);
        if (rd < (unsigned)NPP) {
            int s = ei[e0 + i];
            int sh = (rd & 1) << 4;
            unsigned old = atomicAdd(&scur[rd >> 1], 1u << sh);
            unsigned rel = (old >> sh) & 0xffffu;
            csr[offs[d] + (int)rel] = s * 16;   // pre-scaled uint4 row offset
        }
    }
}

// ---------------- fused layer, BARRIER-FREE: one wave owns 16 nodes end-to-end ----------------
// Per wave: gather 16 rows (quarter-wave slots, MLP 8) -> per-wave LDS transpose
// (wave-coherent, lgkmcnt only) -> 8x8 MFMA (K=256, single 16-row A-frag) ->
// per-wave LN via same LDS region (aliased; ordering enforced by acc dataflow) -> store.
// No __syncthreads anywhere: waves flow independently, gather pipe never drains.

__global__ __launch_bounds__(256) void k_wave(
        const uint4* __restrict__ xq, const int* __restrict__ csr,
        const int* __restrict__ offs, const int* __restrict__ deg,
        const float* __restrict__ invdeg, const uint4* __restrict__ wp,
        const float* __restrict__ bn, const float* __restrict__ gam,
        const float* __restrict__ bet, float* __restrict__ xout,
        unsigned* __restrict__ b16out, int write_f32) {
    __shared__ uint4 AH[4][544];    // per-wave: A = 16x17 uint4 (272) / H = 16x132 fp32 (528 uint4), aliased

    const int t = threadIdx.x;
    const int wv = t >> 6;
    const int lane = t & 63;
    const int slot = lane >> 4;     // edge slot 0..3
    const int m = lane & 15;        // uint4 index within row
    uint4* A = AH[wv];
    float* H = (float*)AH[wv];

    int n0 = (blockIdx.x * 4 + wv) * 16;
    if (n0 > N_NODES - 16) n0 = N_NODES - 16;   // tail waves duplicate last tile (same-value writes, benign)
    const uint4* xm = xq + m;

    // ---- phase 1: aggregate 16 nodes ----
    for (int i = 0; i < 16; ++i) {
        int node = __builtin_amdgcn_readfirstlane(n0 + i);
        const int beg = offs[node];
        const int dn = deg[node];
        float a0 = 0.f, a1 = 0.f, a2 = 0.f, a3 = 0.f, a4 = 0.f, a5 = 0.f, a6 = 0.f, a7 = 0.f;
        int j = slot;
        for (; j + 32 <= dn; j += 32) {     // 8 gathers in flight per lane
            int s0 = csr[beg + j];
            int s1 = csr[beg + j + 4];
            int s2 = csr[beg + j + 8];
            int s3 = csr[beg + j + 12];
            int s4 = csr[beg + j + 16];
            int s5 = csr[beg + j + 20];
            int s6 = csr[beg + j + 24];
            int s7 = csr[beg + j + 28];
            uint4 u0 = xm[s0], u1 = xm[s1], u2 = xm[s2], u3 = xm[s3];
            uint4 u4 = xm[s4], u5 = xm[s5], u6 = xm[s6], u7 = xm[s7];
            a0 += ((bf_lo(u0.x) + bf_lo(u1.x)) + (bf_lo(u2.x) + bf_lo(u3.x))) + ((bf_lo(u4.x) + bf_lo(u5.x)) + (bf_lo(u6.x) + bf_lo(u7.x)));
            a1 += ((bf_hi(u0.x) + bf_hi(u1.x)) + (bf_hi(u2.x) + bf_hi(u3.x))) + ((bf_hi(u4.x) + bf_hi(u5.x)) + (bf_hi(u6.x) + bf_hi(u7.x)));
            a2 += ((bf_lo(u0.y) + bf_lo(u1.y)) + (bf_lo(u2.y) + bf_lo(u3.y))) + ((bf_lo(u4.y) + bf_lo(u5.y)) + (bf_lo(u6.y) + bf_lo(u7.y)));
            a3 += ((bf_hi(u0.y) + bf_hi(u1.y)) + (bf_hi(u2.y) + bf_hi(u3.y))) + ((bf_hi(u4.y) + bf_hi(u5.y)) + (bf_hi(u6.y) + bf_hi(u7.y)));
            a4 += ((bf_lo(u0.z) + bf_lo(u1.z)) + (bf_lo(u2.z) + bf_lo(u3.z))) + ((bf_lo(u4.z) + bf_lo(u5.z)) + (bf_lo(u6.z) + bf_lo(u7.z)));
            a5 += ((bf_hi(u0.z) + bf_hi(u1.z)) + (bf_hi(u2.z) + bf_hi(u3.z))) + ((bf_hi(u4.z) + bf_hi(u5.z)) + (bf_hi(u6.z) + bf_hi(u7.z)));
            a6 += ((bf_lo(u0.w) + bf_lo(u1.w)) + (bf_lo(u2.w) + bf_lo(u3.w))) + ((bf_lo(u4.w) + bf_lo(u5.w)) + (bf_lo(u6.w) + bf_lo(u7.w)));
            a7 += ((bf_hi(u0.w) + bf_hi(u1.w)) + (bf_hi(u2.w) + bf_hi(u3.w))) + ((bf_hi(u4.w) + bf_hi(u5.w)) + (bf_hi(u6.w) + bf_hi(u7.w)));
        }
        for (; j + 16 <= dn; j += 16) {
            int s0 = csr[beg + j];
            int s1 = csr[beg + j + 4];
            int s2 = csr[beg + j + 8];
            int s3 = csr[beg + j + 12];
            uint4 u0 = xm[s0], u1 = xm[s1], u2 = xm[s2], u3 = xm[s3];
            a0 += (bf_lo(u0.x) + bf_lo(u1.x)) + (bf_lo(u2.x) + bf_lo(u3.x));
            a1 += (bf_hi(u0.x) + bf_hi(u1.x)) + (bf_hi(u2.x) + bf_hi(u3.x));
            a2 += (bf_lo(u0.y) + bf_lo(u1.y)) + (bf_lo(u2.y) + bf_lo(u3.y));
            a3 += (bf_hi(u0.y) + bf_hi(u1.y)) + (bf_hi(u2.y) + bf_hi(u3.y));
            a4 += (bf_lo(u0.z) + bf_lo(u1.z)) + (bf_lo(u2.z) + bf_lo(u3.z));
            a5 += (bf_hi(u0.z) + bf_hi(u1.z)) + (bf_hi(u2.z) + bf_hi(u3.z));
            a6 += (bf_lo(u0.w) + bf_lo(u1.w)) + (bf_lo(u2.w) + bf_lo(u3.w));
            a7 += (bf_hi(u0.w) + bf_hi(u1.w)) + (bf_hi(u2.w) + bf_hi(u3.w));
        }
        for (; j < dn; j += 4) {
            uint4 u0 = xm[csr[beg + j]];
            a0 += bf_lo(u0.x); a1 += bf_hi(u0.x);
            a2 += bf_lo(u0.y); a3 += bf_hi(u0.y);
            a4 += bf_lo(u0.z); a5 += bf_hi(u0.z);
            a6 += bf_lo(u0.w); a7 += bf_hi(u0.w);
        }
#pragma unroll
        for (int msk = 16; msk < 64; msk <<= 1) {
            a0 += __shfl_xor(a0, msk); a1 += __shfl_xor(a1, msk);
            a2 += __shfl_xor(a2, msk); a3 += __shfl_xor(a3, msk);
            a4 += __shfl_xor(a4, msk); a5 += __shfl_xor(a5, msk);
            a6 += __shfl_xor(a6, msk); a7 += __shfl_xor(a7, msk);
        }
        if (slot == 0) {
            float id = invdeg[node];
            uint4 r;
            r.x = bf_pack(a0 * id, a1 * id);
            r.y = bf_pack(a2 * id, a3 * id);
            r.z = bf_pack(a4 * id, a5 * id);
            r.w = bf_pack(a6 * id, a7 * id);
            A[i * 17 + m] = r;   // wave-coherent; GEMM reads ordered via lgkmcnt
        }
    }

    // ---- phase 2: MFMA GEMM — 16 rows x 128 cols, K=256, 64 MFMAs ----
    const int quad = lane >> 4;
    const int nl = lane & 15;
    floatx4 acc[8];
#pragma unroll
    for (int nt = 0; nt < 8; ++nt) acc[nt] = (floatx4){0.f, 0.f, 0.f, 0.f};

#pragma unroll
    for (int kb = 0; kb < 8; ++kb) {
        uint4 av = (kb < 4) ? A[nl * 17 + kb * 4 + quad]
                            : xq[(n0 + nl) * 16 + (kb - 4) * 4 + quad];
        short8 as = *(short8*)&av;
#pragma unroll
        for (int nt = 0; nt < 8; ++nt) {
            uint4 bv = wp[(kb * 128 + nt * 16 + nl) * 4 + quad];
            short8 bs = *(short8*)&bv;
            acc[nt] = __builtin_amdgcn_mfma_f32_16x16x32_bf16(as, bs, acc[nt], 0, 0, 0);
        }
    }

    // ---- phase 3: bias -> H (aliases A; safe: H writes depend on final accs) ----
    float bb = bn[quad * 32 + nl];          // placeholder read pattern replaced below
#pragma unroll
    for (int nt = 0; nt < 8; ++nt) {
        float bnv = bn[nt * 16 + nl];
#pragma unroll
        for (int reg = 0; reg < 4; ++reg) {
            H[(quad * 4 + reg) * 132 + nt * 16 + nl] = acc[nt][reg] + bnv;
        }
    }
    (void)bb;

    // ---- phase 4: per-wave LayerNorm + ReLU + store (row = lane&15, 4 lanes x 32 cols) ----
    const int row = lane & 15;
    const int sub = lane >> 4;              // 0..3, cols sub*32..+31
    const float* hr = &H[row * 132 + sub * 32];
    float v[32];
    float s = 0.f, s2 = 0.f;
#pragma unroll
    for (int i = 0; i < 32; i++) {
        v[i] = hr[i];
        s += v[i];
        s2 += v[i] * v[i];
    }
    s += __shfl_xor(s, 16); s2 += __shfl_xor(s2, 16);
    s += __shfl_xor(s, 32); s2 += __shfl_xor(s2, 32);
    float mean = s * (1.f / 128.f);
    float var = s2 * (1.f / 128.f) - mean * mean;
    float rstd = rsqrtf(var + 1e-5f);
    const int gr = n0 + row;
    const int cb = sub * 32;
    float o[32];
#pragma unroll
    for (int i = 0; i < 32; i++) {
        int c = cb + i;
        o[i] = fmaxf((v[i] - mean) * rstd * gam[c] + bet[c], 0.f);
    }
    if (write_f32) {
#pragma unroll
        for (int i = 0; i < 32; i += 4)
            *(float4*)&xout[(size_t)gr * HID + cb + i] = *(float4*)&o[i];
    }
    unsigned p[16];
#pragma unroll
    for (int i = 0; i < 16; i++) p[i] = bf_pack(o[2 * i], o[2 * i + 1]);
#pragma unroll
    for (int i = 0; i < 16; i += 4)
        *(uint4*)&b16out[(size_t)gr * 64 + (cb >> 1) + i] = *(uint4*)&p[i];
}

// ---------------- graph mean-pool: segmented reduction, 1024 threads (16 rows in flight) ----------------

__global__ __launch_bounds__(1024) void k_pool_seg(const unsigned* __restrict__ xb,
                                                   const int* __restrict__ batch,
                                                   float* __restrict__ out) {
    const int g = blockIdx.x;          // 0..63
    __shared__ int s_beg, s_end;
    if (threadIdx.x == 0) {
        int lo = 0, hi = N_NODES;
        while (lo < hi) { int mid = (lo + hi) >> 1; if (batch[mid] < g) lo = mid + 1; else hi = mid; }
        s_beg = lo;
        lo = 0; hi = N_NODES;
        while (lo < hi) { int mid = (lo + hi) >> 1; if (batch[mid] < g + 1) lo = mid + 1; else hi = mid; }
        s_end = lo;
    }
    __syncthreads();
    const int beg = s_beg, end = s_end;
    const int w = threadIdx.x & 63;    // u32 word (2 cols)
    const int q = threadIdx.x >> 6;    // row group 0..15
    float ax = 0.f, ay = 0.f;
    for (int r = beg + q; r < end; r += 16) {
        unsigned u = xb[(size_t)r * 64 + w];
        ax += bf_lo(u);
        ay += bf_hi(u);
    }
    __shared__ float sx[16][64], sy[16][64];
    sx[q][w] = ax;
    sy[q][w] = ay;
    __syncthreads();
    if (q == 0) {
        float tx = 0.f, ty = 0.f;
#pragma unroll
        for (int i = 0; i < 16; i++) { tx += sx[i][w]; ty += sy[i][w]; }
        float inv = 1.f / fmaxf((float)(end - beg), 1.f);
        float2 r;
        r.x = tx * inv;
        r.y = ty * inv;
        *(float2*)&out[(g << 7) + w * 2] = r;
    }
}

extern "C" void kernel_launch(void* const* d_in, const int* in_sizes, int n_in,
                              void* d_out, int out_size, void* d_ws, size_t ws_size,
                              hipStream_t stream) {
    const float* x0 = (const float*)d_in[0];
    const float* Wn = (const float*)d_in[1];
    const float* bn = (const float*)d_in[2];
    const float* Wr = (const float*)d_in[3];
    const float* gam = (const float*)d_in[4];
    const float* bet = (const float*)d_in[5];
    const int* ei = (const int*)d_in[6];
    const int* batch = (const int*)d_in[7];

    float* out = (float*)d_out;                 // [0,8192): graph_emb ; [8192,...): node_emb
    float* node_out = out + N_GRAPHS * HID;

    unsigned* ws = (unsigned*)d_ws;
    int* deg = (int*)(ws + WS_DEG);
    int* bsum = (int*)(ws + WS_BSUM);
    int* boff = (int*)(ws + WS_BOFF);
    int* offs = (int*)(ws + WS_OFFS);
    float* invdeg = (float*)(ws + WS_INVD);
    int* csr = (int*)(ws + WS_CSR);
    unsigned* hist = ws + WS_XB_B;    // hist during build; x buffer B after
    unsigned* xa = ws + WS_XB_A;      // x buffer A
    unsigned* xbb = ws + WS_XB_B;
    uint4* wp = (uint4*)(ws + WS_WP);

    const int nb = (N_NODES + 255) / 256;          // 196
    k_cvt<<<(N_NODES * HID / 4) / 256, 256, 0, stream>>>((const float4*)x0, (uint2*)xa);
    k_packw<<<48, 256, 0, stream>>>(Wn, Wr, wp);
    k_hist<<<HIST_BLOCKS, 256, 0, stream>>>(ei, hist);
    k_scanb<<<(NWORDS + 255) / 256, 256, 0, stream>>>(hist, deg);
    k_blockreduce<<<nb, 256, 0, stream>>>(deg, bsum);
    k_scanblocks<<<1, 256, 0, stream>>>(bsum, boff, nb);
    k_offsets<<<nb, 256, 0, stream>>>(deg, boff, offs, invdeg);
    k_fill2<<<HIST_BLOCKS * FILL_PASSES, 256, 0, stream>>>(ei, offs, hist, csr);

    const int wb = (N_NODES / 16 + 3) / 4;         // 782 blocks (4 waves x 16 nodes each)

    // ping-pong: l0 A->B, l1 B->A, l2 A->B (fused layer cannot run in-place)
    for (int l = 0; l < 3; ++l) {
        const unsigned* xin = (l & 1) ? xbb : xa;
        unsigned* xout16 = (l & 1) ? xa : xbb;
        k_wave<<<wb, 256, 0, stream>>>((const uint4*)xin, csr, offs, deg, invdeg,
                                       wp + (size_t)l * 4096, bn + (size_t)l * HID,
                                       gam + (size_t)l * HID, bet + (size_t)l * HID,
                                       node_out, xout16, l == 2 ? 1 : 0);
    }

    k_pool_seg<<<N_GRAPHS, 1024, 0, stream>>>(xbb, batch, out);
}

// Round 10
// 466.044 us; speedup vs baseline: 1.2565x; 1.2565x over previous
//
#include <hip/hip_runtime.h>

#define N_NODES 50000
#define N_EDGES 1600000
#define HID     128
#define N_GRAPHS 64

#define HB 256                            // hist blocks (slices)
#define EPB (N_EDGES / HB)                // 6250 edges per slice
#define HWORDS 12500                      // 50000 nodes packed u8 x4 per word
#define NPP 12500                         // nodes per fill pass
#define CWPP (NPP / 4)                    // 3125 cursor words per pass (u8)

// workspace layout (4-byte words) — 8.2M words = 32.8 MB
#define WS_DEG   0u         // int[50000]
#define WS_BSUM  50000u     // int[256]
#define WS_BOFF  50256u     // int[256]
#define WS_OFFS  50512u     // int[50000]
#define WS_INVD  100512u    // float[50000]
#define WS_CSR   150512u    // int[1600000]
#define WS_XB_B  1750512u   // uint[3200000]: hist u8[256][12500w] during build; x ping buffer B after
#define WS_XB_A  4950512u   // uint[3200000]: x ping buffer A (bf16 x2: 50000x128)
#define WS_WP    8150512u   // uint[49152] = packed W frags: 3 layers x 4096 uint4
#define WS_END   8199664u

typedef __attribute__((ext_vector_type(8))) short short8;
typedef __attribute__((ext_vector_type(4))) float floatx4;

// ---- bf16 helpers (raw, RN-even pack; fp32 math everywhere) ----
__device__ __forceinline__ float bf_lo(unsigned u) { return __uint_as_float(u << 16); }
__device__ __forceinline__ float bf_hi(unsigned u) { return __uint_as_float(u & 0xffff0000u); }
__device__ __forceinline__ unsigned bf_rn(float f) {
    unsigned u = __float_as_uint(f);
    unsigned r = ((u >> 16) & 1u) + 0x7fffu;
    return (u + r) >> 16;
}
__device__ __forceinline__ unsigned bf_pack(float lo, float hi) {
    return bf_rn(lo) | (bf_rn(hi) << 16);
}

// ---------------- prep: x0 fp32->bf16 (blocks 0..6249) + W pack (blocks 6250..6297) ----------------
__global__ __launch_bounds__(256) void k_prep(const float4* __restrict__ x, uint2* __restrict__ o,
                                              const float* __restrict__ Wn, const float* __restrict__ Wr,
                                              uint4* __restrict__ wp) {
    if (blockIdx.x < 6250) {
        int i = blockIdx.x * 256 + threadIdx.x;      // 1.6M total
        float4 v = x[i];
        uint2 r;
        r.x = bf_pack(v.x, v.y);
        r.y = bf_pack(v.z, v.w);
        o[i] = r;
    } else {
        int idx = (blockIdx.x - 6250) * 256 + threadIdx.x;   // 12288 total
        int layer = idx >> 12;
        int rem = idx & 4095;
        int kb = rem >> 9;
        int n = (rem >> 2) & 127;
        int quad = rem & 3;
        float v[8];
#pragma unroll
        for (int j = 0; j < 8; j++) {
            int k = kb * 32 + quad * 8 + j;
            v[j] = (k < 128) ? Wn[layer * 16384 + k * 128 + n]
                             : Wr[layer * 16384 + (k - 128) * 128 + n];
        }
        uint4 r;
        r.x = bf_pack(v[0], v[1]);
        r.y = bf_pack(v[2], v[3]);
        r.z = bf_pack(v[4], v[5]);
        r.w = bf_pack(v[6], v[7]);
        wp[idx] = r;
    }
}

// ---------------- CSR build: atomic-free, u8-packed (256 slices) ----------------

// Stage 1: per-slice LDS histogram, u8 x4 per word (per-slice per-node count << 255).
__global__ __launch_bounds__(256) void k_hist(const int* __restrict__ ei, unsigned* __restrict__ hist) {
    __shared__ unsigned sh[HWORDS];   // 50 KB
    for (int i = threadIdx.x; i < HWORDS; i += 256) sh[i] = 0;
    __syncthreads();
    const int e0 = blockIdx.x * EPB;
    for (int i = threadIdx.x; i < EPB; i += 256) {
        int d = __builtin_nontemporal_load(ei + N_EDGES + e0 + i);
        atomicAdd(&sh[d >> 2], 1u << ((d & 3) << 3));
    }
    __syncthreads();
    unsigned* hb = hist + (size_t)blockIdx.x * HWORDS;
    for (int i = threadIdx.x; i < HWORDS; i += 256) hb[i] = sh[i];
}

// Stage 2: exclusive scan over 256 slice-partials per node (byte fields independent,
// total deg << 255 so no carry). Emits deg + per-block (1024-node) sums.
__global__ __launch_bounds__(256) void k_scanb(unsigned* __restrict__ hist, int* __restrict__ deg,
                                               int* __restrict__ bsum) {
    int w = blockIdx.x * 256 + threadIdx.x;
    int mysum = 0;
    if (w < HWORDS) {
        unsigned run = 0;
#pragma unroll 8
        for (int b = 0; b < HB; ++b) {
            unsigned u = hist[(size_t)b * HWORDS + w];
            hist[(size_t)b * HWORDS + w] = run;
            run += u;
        }
#pragma unroll
        for (int k = 0; k < 4; ++k) {
            int d = (int)((run >> (k << 3)) & 0xffu);
            deg[4 * w + k] = d;
            mysum += d;
        }
    }
    __shared__ int s[256];
    s[threadIdx.x] = mysum;
    __syncthreads();
    for (int d = 128; d > 0; d >>= 1) {
        if (threadIdx.x < d) s[threadIdx.x] += s[threadIdx.x + d];
        __syncthreads();
    }
    if (threadIdx.x == 0) bsum[blockIdx.x] = s[0];
}

__global__ __launch_bounds__(256) void k_scanblocks(const int* __restrict__ bsum, int* __restrict__ boff, int nb) {
    __shared__ int s[256];
    int t = threadIdx.x;
    int v = (t < nb) ? bsum[t] : 0;
    s[t] = v;
    __syncthreads();
    for (int d = 1; d < 256; d <<= 1) {
        int add = (t >= d) ? s[t - d] : 0;
        __syncthreads();
        s[t] += add;
        __syncthreads();
    }
    if (t < nb) boff[t] = s[t] - v;   // exclusive
}

// Stage 3: global offsets + invdeg; 4 nodes per thread, 1024 nodes per block.
__global__ __launch_bounds__(256) void k_offsets(const int* __restrict__ deg, const int* __restrict__ boff,
                                                 int* __restrict__ offs, float* __restrict__ invdeg) {
    __shared__ int s[256];
    int b = blockIdx.x, t = threadIdx.x;
    int n0 = (b * 256 + t) * 4;
    int d[4] = {0, 0, 0, 0};
#pragma unroll
    for (int k = 0; k < 4; ++k)
        if (n0 + k < N_NODES) d[k] = deg[n0 + k];
    int v = d[0] + d[1] + d[2] + d[3];
    s[t] = v;
    __syncthreads();
    for (int dd = 1; dd < 256; dd <<= 1) {
        int add = (t >= dd) ? s[t - dd] : 0;
        __syncthreads();
        s[t] += add;
        __syncthreads();
    }
    int base = boff[b] + s[t] - v;
#pragma unroll
    for (int k = 0; k < 4; ++k) {
        if (n0 + k < N_NODES) {
            offs[n0 + k] = base;
            invdeg[n0 + k] = 1.0f / fmaxf((float)d[k], 1.0f);
            base += d[k];
        }
    }
}

// Stage 4: fill — 256 slices x 4 node-range passes = 1024 concurrent blocks; u8 LDS
// cursors (base = scanned per-slice prefix). csr stores PRE-SCALED uint4 offsets.
__global__ __launch_bounds__(256) void k_fill(const int* __restrict__ ei, const int* __restrict__ offs,
                                              const unsigned* __restrict__ hist, int* __restrict__ csr) {
    __shared__ unsigned scur[CWPP];   // 12.5 KB
    const int s8 = blockIdx.x & 7;
    const int pass = s8 >> 1;                              // 0..3 (XCD pair per csr quarter)
    const int b = ((blockIdx.x >> 3) << 1) | (s8 & 1);     // 0..255 edge slice
    const int nbase = pass * NPP;
    const unsigned* hb = hist + (size_t)b * HWORDS + pass * CWPP;
    for (int i = threadIdx.x; i < CWPP; i += 256) scur[i] = hb[i];
    __syncthreads();
    const int e0 = b * EPB;
    for (int i = threadIdx.x; i < EPB; i += 256) {
        int d = __builtin_nontemporal_load(ei + N_EDGES + e0 + i);
        unsigned rd = (unsigned)(d - nbase);
        if (rd < (unsigned)NPP) {
            int s = ei[e0 + i];
            int sh = (rd & 3) << 3;
            unsigned old = atomicAdd(&scur[rd >> 2], 1u << sh);
            unsigned rel = (old >> sh) & 0xffu;
            csr[offs[d] + (int)rel] = s * 16;   // pre-scaled uint4 row offset
        }
    }
}

// ---------------- fused layer: 16 nodes/block, 4 waves ----------------
// Phase 1: wave w aggregates nodes w*4..w*4+3 (quarter-wave edge slots, 8-deep MLP),
// bf16 rows into LDS A (stride 17 uint4). Phase 2: all 4 waves MFMA 16x128, K=256
// (A from LDS, x-self rows direct from global, B pre-packed). Phase 3/4: bias+LN+ReLU.
// LDS = union(A 4.3KB, H 8.4KB) = 8.4KB -> occupancy capped by waves (32/CU), not LDS.

__global__ __launch_bounds__(256) void k_layer16(
        const uint4* __restrict__ xq, const int* __restrict__ csr,
        const int* __restrict__ offs, const int* __restrict__ deg,
        const float* __restrict__ invdeg, const uint4* __restrict__ wp,
        const float* __restrict__ bn, const float* __restrict__ gam,
        const float* __restrict__ bet, float* __restrict__ xout,
        unsigned* __restrict__ b16out, int write_f32) {
    __shared__ float H[16 * 132];              // 8448 B; A aliases the front
    uint4* A = (uint4*)H;                      // A = uint4[16*17] = 4352 B

    const int t = threadIdx.x;
    const int wv = t >> 6;
    const int lane = t & 63;
    const int slot = lane >> 4;     // edge slot 0..3
    const int m = lane & 15;        // uint4 index within row
    const int n0 = blockIdx.x * 16; // 50000 = 16*3125 exactly, no tail
    const uint4* xm = xq + m;

    // ---- phase 1: each wave aggregates 4 nodes ----
    for (int i = 0; i < 4; ++i) {
        int node = __builtin_amdgcn_readfirstlane(n0 + wv * 4 + i);
        const int beg = offs[node];
        const int dn = deg[node];
        float a0 = 0.f, a1 = 0.f, a2 = 0.f, a3 = 0.f, a4 = 0.f, a5 = 0.f, a6 = 0.f, a7 = 0.f;
        int j = slot;
        for (; j + 32 <= dn; j += 32) {     // 8 gathers in flight per lane
            int s0 = csr[beg + j];
            int s1 = csr[beg + j + 4];
            int s2 = csr[beg + j + 8];
            int s3 = csr[beg + j + 12];
            int s4 = csr[beg + j + 16];
            int s5 = csr[beg + j + 20];
            int s6 = csr[beg + j + 24];
            int s7 = csr[beg + j + 28];
            uint4 u0 = xm[s0], u1 = xm[s1], u2 = xm[s2], u3 = xm[s3];
            uint4 u4 = xm[s4], u5 = xm[s5], u6 = xm[s6], u7 = xm[s7];
            a0 += ((bf_lo(u0.x) + bf_lo(u1.x)) + (bf_lo(u2.x) + bf_lo(u3.x))) + ((bf_lo(u4.x) + bf_lo(u5.x)) + (bf_lo(u6.x) + bf_lo(u7.x)));
            a1 += ((bf_hi(u0.x) + bf_hi(u1.x)) + (bf_hi(u2.x) + bf_hi(u3.x))) + ((bf_hi(u4.x) + bf_hi(u5.x)) + (bf_hi(u6.x) + bf_hi(u7.x)));
            a2 += ((bf_lo(u0.y) + bf_lo(u1.y)) + (bf_lo(u2.y) + bf_lo(u3.y))) + ((bf_lo(u4.y) + bf_lo(u5.y)) + (bf_lo(u6.y) + bf_lo(u7.y)));
            a3 += ((bf_hi(u0.y) + bf_hi(u1.y)) + (bf_hi(u2.y) + bf_hi(u3.y))) + ((bf_hi(u4.y) + bf_hi(u5.y)) + (bf_hi(u6.y) + bf_hi(u7.y)));
            a4 += ((bf_lo(u0.z) + bf_lo(u1.z)) + (bf_lo(u2.z) + bf_lo(u3.z))) + ((bf_lo(u4.z) + bf_lo(u5.z)) + (bf_lo(u6.z) + bf_lo(u7.z)));
            a5 += ((bf_hi(u0.z) + bf_hi(u1.z)) + (bf_hi(u2.z) + bf_hi(u3.z))) + ((bf_hi(u4.z) + bf_hi(u5.z)) + (bf_hi(u6.z) + bf_hi(u7.z)));
            a6 += ((bf_lo(u0.w) + bf_lo(u1.w)) + (bf_lo(u2.w) + bf_lo(u3.w))) + ((bf_lo(u4.w) + bf_lo(u5.w)) + (bf_lo(u6.w) + bf_lo(u7.w)));
            a7 += ((bf_hi(u0.w) + bf_hi(u1.w)) + (bf_hi(u2.w) + bf_hi(u3.w))) + ((bf_hi(u4.w) + bf_hi(u5.w)) + (bf_hi(u6.w) + bf_hi(u7.w)));
        }
        for (; j + 16 <= dn; j += 16) {
            int s0 = csr[beg + j];
            int s1 = csr[beg + j + 4];
            int s2 = csr[beg + j + 8];
            int s3 = csr[beg + j + 12];
            uint4 u0 = xm[s0], u1 = xm[s1], u2 = xm[s2], u3 = xm[s3];
            a0 += (bf_lo(u0.x) + bf_lo(u1.x)) + (bf_lo(u2.x) + bf_lo(u3.x));
            a1 += (bf_hi(u0.x) + bf_hi(u1.x)) + (bf_hi(u2.x) + bf_hi(u3.x));
            a2 += (bf_lo(u0.y) + bf_lo(u1.y)) + (bf_lo(u2.y) + bf_lo(u3.y));
            a3 += (bf_hi(u0.y) + bf_hi(u1.y)) + (bf_hi(u2.y) + bf_hi(u3.y));
            a4 += (bf_lo(u0.z) + bf_lo(u1.z)) + (bf_lo(u2.z) + bf_lo(u3.z));
            a5 += (bf_hi(u0.z) + bf_hi(u1.z)) + (bf_hi(u2.z) + bf_hi(u3.z));
            a6 += (bf_lo(u0.w) + bf_lo(u1.w)) + (bf_lo(u2.w) + bf_lo(u3.w));
            a7 += (bf_hi(u0.w) + bf_hi(u1.w)) + (bf_hi(u2.w) + bf_hi(u3.w));
        }
        for (; j < dn; j += 4) {
            uint4 u0 = xm[csr[beg + j]];
            a0 += bf_lo(u0.x); a1 += bf_hi(u0.x);
            a2 += bf_lo(u0.y); a3 += bf_hi(u0.y);
            a4 += bf_lo(u0.z); a5 += bf_hi(u0.z);
            a6 += bf_lo(u0.w); a7 += bf_hi(u0.w);
        }
#pragma unroll
        for (int msk = 16; msk < 64; msk <<= 1) {
            a0 += __shfl_xor(a0, msk); a1 += __shfl_xor(a1, msk);
            a2 += __shfl_xor(a2, msk); a3 += __shfl_xor(a3, msk);
            a4 += __shfl_xor(a4, msk); a5 += __shfl_xor(a5, msk);
            a6 += __shfl_xor(a6, msk); a7 += __shfl_xor(a7, msk);
        }
        if (slot == 0) {
            float id = invdeg[node];
            uint4 r;
            r.x = bf_pack(a0 * id, a1 * id);
            r.y = bf_pack(a2 * id, a3 * id);
            r.z = bf_pack(a4 * id, a5 * id);
            r.w = bf_pack(a6 * id, a7 * id);
            A[(wv * 4 + i) * 17 + m] = r;
        }
    }
    __syncthreads();

    // ---- phase 2: MFMA GEMM — 16 rows x 128 cols, K=256; wave w owns cols w*32..+31 ----
    const int quad = lane >> 4;
    const int nl = lane & 15;
    const int nb = wv * 32;
    floatx4 acc0 = {0.f, 0.f, 0.f, 0.f}, acc1 = acc0;
#pragma unroll
    for (int kb = 0; kb < 8; ++kb) {
        uint4 av = (kb < 4) ? A[nl * 17 + kb * 4 + quad]
                            : xq[(n0 + nl) * 16 + (kb - 4) * 4 + quad];
        uint4 b0 = wp[(kb * 128 + nb + nl) * 4 + quad];
        uint4 b1 = wp[(kb * 128 + nb + 16 + nl) * 4 + quad];
        short8 as = *(short8*)&av;
        short8 b0s = *(short8*)&b0, b1s = *(short8*)&b1;
        acc0 = __builtin_amdgcn_mfma_f32_16x16x32_bf16(as, b0s, acc0, 0, 0, 0);
        acc1 = __builtin_amdgcn_mfma_f32_16x16x32_bf16(as, b1s, acc1, 0, 0, 0);
    }
    __syncthreads();   // A (aliased by H) fully read by all waves

    // ---- phase 3: bias -> H ----
    float bn0 = bn[nb + nl];
    float bn1 = bn[nb + 16 + nl];
#pragma unroll
    for (int reg = 0; reg < 4; ++reg) {
        int rr = quad * 4 + reg;
        H[rr * 132 + nb + nl] = acc0[reg] + bn0;
        H[rr * 132 + nb + 16 + nl] = acc1[reg] + bn1;
    }
    __syncthreads();

    // ---- phase 4: LayerNorm + ReLU + store (16 threads/row, 8 cols each) ----
    const int row = t >> 4;    // 0..15
    const int sub = t & 15;
    const float* hr = &H[row * 132 + sub * 8];
    float v[8];
    float s = 0.f, s2 = 0.f;
#pragma unroll
    for (int i = 0; i < 8; i++) {
        v[i] = hr[i];
        s += v[i];
        s2 += v[i] * v[i];
    }
#pragma unroll
    for (int msk = 1; msk < 16; msk <<= 1) {
        s += __shfl_xor(s, msk);
        s2 += __shfl_xor(s2, msk);
    }
    float mean = s * (1.f / 128.f);
    float var = s2 * (1.f / 128.f) - mean * mean;
    float rstd = rsqrtf(var + 1e-5f);
    const int gr = n0 + row;
    const int cb = sub * 8;
    float o[8];
#pragma unroll
    for (int i = 0; i < 8; i++)
        o[i] = fmaxf((v[i] - mean) * rstd * gam[cb + i] + bet[cb + i], 0.f);
    if (write_f32) {
        *(float4*)&xout[(size_t)gr * HID + cb] = *(float4*)&o[0];
        *(float4*)&xout[(size_t)gr * HID + cb + 4] = *(float4*)&o[4];
    }
    unsigned p[4];
#pragma unroll
    for (int i = 0; i < 4; i++) p[i] = bf_pack(o[2 * i], o[2 * i + 1]);
    *(uint4*)&b16out[(size_t)gr * 64 + (cb >> 1)] = *(uint4*)&p[0];
}

// ---------------- graph mean-pool: segmented reduction, 1024 threads ----------------

__global__ __launch_bounds__(1024) void k_pool_seg(const unsigned* __restrict__ xb,
                                                   const int* __restrict__ batch,
                                                   float* __restrict__ out) {
    const int g = blockIdx.x;          // 0..63
    __shared__ int s_beg, s_end;
    if (threadIdx.x == 0) {
        int lo = 0, hi = N_NODES;
        while (lo < hi) { int mid = (lo + hi) >> 1; if (batch[mid] < g) lo = mid + 1; else hi = mid; }
        s_beg = lo;
        lo = 0; hi = N_NODES;
        while (lo < hi) { int mid = (lo + hi) >> 1; if (batch[mid] < g + 1) lo = mid + 1; else hi = mid; }
        s_end = lo;
    }
    __syncthreads();
    const int beg = s_beg, end = s_end;
    const int w = threadIdx.x & 63;    // u32 word (2 cols)
    const int q = threadIdx.x >> 6;    // row group 0..15
    float ax = 0.f, ay = 0.f;
    for (int r = beg + q; r < end; r += 16) {
        unsigned u = xb[(size_t)r * 64 + w];
        ax += bf_lo(u);
        ay += bf_hi(u);
    }
    __shared__ float sx[16][64], sy[16][64];
    sx[q][w] = ax;
    sy[q][w] = ay;
    __syncthreads();
    if (q == 0) {
        float tx = 0.f, ty = 0.f;
#pragma unroll
        for (int i = 0; i < 16; i++) { tx += sx[i][w]; ty += sy[i][w]; }
        float inv = 1.f / fmaxf((float)(end - beg), 1.f);
        float2 r;
        r.x = tx * inv;
        r.y = ty * inv;
        *(float2*)&out[(g << 7) + w * 2] = r;
    }
}

extern "C" void kernel_launch(void* const* d_in, const int* in_sizes, int n_in,
                              void* d_out, int out_size, void* d_ws, size_t ws_size,
                              hipStream_t stream) {
    const float* x0 = (const float*)d_in[0];
    const float* Wn = (const float*)d_in[1];
    const float* bn = (const float*)d_in[2];
    const float* Wr = (const float*)d_in[3];
    const float* gam = (const float*)d_in[4];
    const float* bet = (const float*)d_in[5];
    const int* ei = (const int*)d_in[6];
    const int* batch = (const int*)d_in[7];

    float* out = (float*)d_out;                 // [0,8192): graph_emb ; [8192,...): node_emb
    float* node_out = out + N_GRAPHS * HID;

    unsigned* ws = (unsigned*)d_ws;
    int* deg = (int*)(ws + WS_DEG);
    int* bsum = (int*)(ws + WS_BSUM);
    int* boff = (int*)(ws + WS_BOFF);
    int* offs = (int*)(ws + WS_OFFS);
    float* invdeg = (float*)(ws + WS_INVD);
    int* csr = (int*)(ws + WS_CSR);
    unsigned* hist = ws + WS_XB_B;    // hist during build; x buffer B after
    unsigned* xa = ws + WS_XB_A;      // x buffer A
    unsigned* xbb = ws + WS_XB_B;
    uint4* wp = (uint4*)(ws + WS_WP);

    k_prep<<<6298, 256, 0, stream>>>((const float4*)x0, (uint2*)xa, Wn, Wr, wp);
    k_hist<<<HB, 256, 0, stream>>>(ei, hist);
    k_scanb<<<49, 256, 0, stream>>>(hist, deg, bsum);
    k_scanblocks<<<1, 256, 0, stream>>>(bsum, boff, 49);
    k_offsets<<<49, 256, 0, stream>>>(deg, boff, offs, invdeg);
    k_fill<<<HB * 4, 256, 0, stream>>>(ei, offs, hist, csr);

    const int lb = N_NODES / 16;                   // 3125 blocks

    // ping-pong: l0 A->B, l1 B->A, l2 A->B (fused layer cannot run in-place)
    for (int l = 0; l < 3; ++l) {
        const unsigned* xin = (l & 1) ? xbb : xa;
        unsigned* xout16 = (l & 1) ? xa : xbb;
        k_layer16<<<lb, 256, 0, stream>>>((const uint4*)xin, csr, offs, deg, invdeg,
                                          wp + (size_t)l * 4096, bn + (size_t)l * HID,
                                          gam + (size_t)l * HID, bet + (size_t)l * HID,
                                          node_out, xout16, l == 2 ? 1 : 0);
    }

    k_pool_seg<<<N_GRAPHS, 1024, 0, stream>>>(xbb, batch, out);
}